// Round 1
// baseline (1030.686 us; speedup 1.0000x reference)
//
#include <hip/hip_runtime.h>
#include <stdint.h>

#define B_DIM 8
#define T_DIM 4096
#define K_DIM 1024
#define H_DIM 1024
#define M_DIM (B_DIM * T_DIM)      // 32768
#define CHUNK 64
#define NCHUNK (T_DIM / CHUNK)     // 64

typedef __attribute__((ext_vector_type(8))) short s16x8;
typedef __attribute__((ext_vector_type(4))) float f32x4;

__device__ __forceinline__ unsigned short f2b(float f) {
    union { float f; uint32_t u; } c; c.f = f;
    uint32_t r = (c.u + 0x7fffu + ((c.u >> 16) & 1u)) >> 16;
    return (unsigned short)r;
}
__device__ __forceinline__ float b2f(unsigned short u) {
    union { uint32_t u; float f; } c; c.u = ((uint32_t)u) << 16;
    return c.f;
}

// ---------------- conversion kernels ----------------

__global__ void cvt_f32_bf16(const float* __restrict__ src,
                             unsigned short* __restrict__ dst, int n4) {
    int stride = gridDim.x * blockDim.x;
    for (int i = blockIdx.x * blockDim.x + threadIdx.x; i < n4; i += stride) {
        float4 v = ((const float4*)src)[i];
        ushort4 o;
        o.x = f2b(v.x); o.y = f2b(v.y); o.z = f2b(v.z); o.w = f2b(v.w);
        ((ushort4*)dst)[i] = o;
    }
}

// W'[2c+0][k] = W_hg[c][k] (hidden row), W'[2c+1][k] = W_hg[H+c][k] (gate row)
__global__ void prep_whg(const float* __restrict__ W,
                         unsigned short* __restrict__ Wp) {
    int i = blockIdx.x * blockDim.x + threadIdx.x;
    int total = 2 * H_DIM * K_DIM / 4;
    if (i >= total) return;
    int e = i * 4;
    int n = e >> 10;          // K = 1024
    int k = e & 1023;
    int src = (n & 1) ? (H_DIM + (n >> 1)) : (n >> 1);
    float4 v = *(const float4*)&W[(size_t)src * K_DIM + k];
    ushort4 o;
    o.x = f2b(v.x); o.y = f2b(v.y); o.z = f2b(v.z); o.w = f2b(v.w);
    *(ushort4*)&Wp[(size_t)n * K_DIM + k] = o;
}

// ---------------- bf16 MFMA GEMM: C[m,n] = sum_k A[m,k] * Bm[n,k] ----------------
// EPI==0: plain f32 store to C (N cols).
// EPI==1: minGRU fused epilogue. Columns interleaved (even=hidden, odd=gate):
//         Sa[row,ch] = 1-sigmoid(gate),  Sb[row,ch] = sigmoid(gate)*hidden (bf16).

template <int EPI>
__global__ __launch_bounds__(256) void gemm_bt(
    const unsigned short* __restrict__ A,
    const unsigned short* __restrict__ Bm,
    float* __restrict__ C,
    unsigned short* __restrict__ Sa,
    unsigned short* __restrict__ Sb,
    int N) {
    __shared__ unsigned short As[128 * 64];
    __shared__ unsigned short Bs[128 * 64];
    const int K = K_DIM;
    const int m0 = blockIdx.y * 128;
    const int n0 = blockIdx.x * 128;
    const int t = threadIdx.x;
    const int lane = t & 63;
    const int wave = t >> 6;
    const int wm = wave >> 1, wn = wave & 1;

    f32x4 acc[4][4];
#pragma unroll
    for (int m = 0; m < 4; m++)
#pragma unroll
        for (int n = 0; n < 4; n++) acc[m][n] = (f32x4){0.f, 0.f, 0.f, 0.f};

    const int srow = t >> 3;          // 0..31
    const int skc  = (t & 7) * 8;     // k element offset for this thread's 16B

    int4 av[4], bv[4];
#pragma unroll
    for (int i = 0; i < 4; i++) {
        av[i] = *(const int4*)&A[(size_t)(m0 + i * 32 + srow) * K + skc];
        bv[i] = *(const int4*)&Bm[(size_t)(n0 + i * 32 + srow) * K + skc];
    }

    const int KT = K / 64;
    for (int kt = 0; kt < KT; ++kt) {
        __syncthreads();
#pragma unroll
        for (int i = 0; i < 4; i++) {
            *(int4*)&As[(i * 32 + srow) * 64 + skc] = av[i];
            *(int4*)&Bs[(i * 32 + srow) * 64 + skc] = bv[i];
        }
        __syncthreads();
        if (kt + 1 < KT) {
            int k0 = (kt + 1) * 64;
#pragma unroll
            for (int i = 0; i < 4; i++) {
                av[i] = *(const int4*)&A[(size_t)(m0 + i * 32 + srow) * K + k0 + skc];
                bv[i] = *(const int4*)&Bm[(size_t)(n0 + i * 32 + srow) * K + k0 + skc];
            }
        }
#pragma unroll
        for (int ks = 0; ks < 2; ++ks) {
            const int l15 = lane & 15;
            const int lk = (lane >> 4) * 8 + ks * 32;
            s16x8 af[4], bf[4];
#pragma unroll
            for (int m = 0; m < 4; m++)
                af[m] = *(const s16x8*)&As[(wm * 64 + m * 16 + l15) * 64 + lk];
#pragma unroll
            for (int n = 0; n < 4; n++)
                bf[n] = *(const s16x8*)&Bs[(wn * 64 + n * 16 + l15) * 64 + lk];
#pragma unroll
            for (int m = 0; m < 4; m++)
#pragma unroll
                for (int n = 0; n < 4; n++)
                    acc[m][n] = __builtin_amdgcn_mfma_f32_16x16x32_bf16(
                        af[m], bf[n], acc[m][n], 0, 0, 0);
        }
    }

    const int l15 = lane & 15;
    const int lr = (lane >> 4) * 4;
#pragma unroll
    for (int m = 0; m < 4; m++) {
#pragma unroll
        for (int n = 0; n < 4; n++) {
#pragma unroll
            for (int r = 0; r < 4; r++) {
                int row = m0 + wm * 64 + m * 16 + lr + r;
                int col = n0 + wn * 64 + n * 16 + l15;
                float v = acc[m][n][r];
                if (EPI == 0) {
                    C[(size_t)row * N + col] = v;
                } else {
                    float o = __shfl_xor(v, 1);
                    int ch = col >> 1;
                    if ((lane & 1) == 0) {
                        // even lane: v = hidden, o = gate logit
                        float g = 1.f / (1.f + __expf(-o));
                        Sb[(size_t)row * H_DIM + ch] = f2b(g * v);
                    } else {
                        // odd lane: v = gate logit
                        float g = 1.f / (1.f + __expf(-v));
                        Sa[(size_t)row * H_DIM + ch] = f2b(1.f - g);
                    }
                }
            }
        }
    }
}

// ---------------- chunked scan ----------------
// Element combine (matches reference): carry (A,Bv); element (a,b,r):
//   r>0 : (A,Bv) = (a, b)      else : (A,Bv) = (a*A, a*Bv + b)

__global__ __launch_bounds__(256) void scan_chunks(
    const unsigned short* __restrict__ Sa, const unsigned short* __restrict__ Sb,
    const float* __restrict__ is_init,
    float* __restrict__ CA, float* __restrict__ CB, float* __restrict__ CR) {
    int idx = blockIdx.x * 256 + threadIdx.x;      // b*65536 + chunk*1024 + ch
    int ch = idx & (H_DIM - 1);
    int chunk = (idx >> 10) & (NCHUNK - 1);
    int b = idx >> 16;
    int t0 = chunk * CHUNK;
    size_t base = ((size_t)b * T_DIM + t0) * H_DIM + ch;
    const float* ii = is_init + (size_t)b * T_DIM + t0;
    float A = 1.f, Bv = 0.f;
    int rf = 0;
    for (int i = 0; i < CHUNK; i++) {
        float a = b2f(Sa[base + (size_t)i * H_DIM]);
        float bb = b2f(Sb[base + (size_t)i * H_DIM]);
        bool rst = ii[i] > 0.f;
        A = rst ? a : a * A;
        Bv = rst ? bb : fmaf(a, Bv, bb);
        rf |= (int)rst;
    }
    size_t o = ((size_t)b * NCHUNK + chunk) * H_DIM + ch;
    CA[o] = A;
    CB[o] = Bv;
    if (ch == 0) CR[b * NCHUNK + chunk] = (float)rf;
}

__global__ void scan_tops(const float* __restrict__ CA, const float* __restrict__ CB,
                          const float* __restrict__ CR,
                          float* __restrict__ PA, float* __restrict__ PB) {
    int idx = blockIdx.x * blockDim.x + threadIdx.x;   // 0 .. B*H-1
    if (idx >= B_DIM * H_DIM) return;
    int ch = idx & (H_DIM - 1);
    int b = idx >> 10;
    float A = 1.f, Bv = 0.f;
    for (int c = 0; c < NCHUNK; c++) {
        size_t o = ((size_t)b * NCHUNK + c) * H_DIM + ch;
        PA[o] = A;            // exclusive prefix
        PB[o] = Bv;
        float a = CA[o], bb = CB[o];
        bool rst = CR[b * NCHUNK + c] > 0.f;
        float nA = rst ? a : a * A;
        float nB = rst ? bb : fmaf(a, Bv, bb);
        A = nA; Bv = nB;
    }
}

__global__ __launch_bounds__(256) void scan_apply(
    const unsigned short* __restrict__ Sa, const unsigned short* __restrict__ Sb,
    const float* __restrict__ is_init,
    const float* __restrict__ PA, const float* __restrict__ PB,
    const float* __restrict__ h0,
    unsigned short* __restrict__ hb, float* __restrict__ hn) {
    int idx = blockIdx.x * 256 + threadIdx.x;
    int ch = idx & (H_DIM - 1);
    int chunk = (idx >> 10) & (NCHUNK - 1);
    int b = idx >> 16;
    int t0 = chunk * CHUNK;
    size_t base = ((size_t)b * T_DIM + t0) * H_DIM + ch;
    const float* ii = is_init + (size_t)b * T_DIM + t0;
    size_t po = ((size_t)b * NCHUNK + chunk) * H_DIM + ch;
    float A = PA[po], Bv = PB[po];
    float h0v = h0[b * H_DIM + ch];
    float h = 0.f;
    for (int i = 0; i < CHUNK; i++) {
        float a = b2f(Sa[base + (size_t)i * H_DIM]);
        float bb = b2f(Sb[base + (size_t)i * H_DIM]);
        bool rst = ii[i] > 0.f;
        A = rst ? a : a * A;
        Bv = rst ? bb : fmaf(a, Bv, bb);
        h = fmaf(A, h0v, Bv);
        hb[base + (size_t)i * H_DIM] = f2b(h);
    }
    if (chunk == NCHUNK - 1) hn[b * H_DIM + ch] = h;
}

// ---------------- launcher ----------------

extern "C" void kernel_launch(void* const* d_in, const int* in_sizes, int n_in,
                              void* d_out, int out_size, void* d_ws, size_t ws_size,
                              hipStream_t stream) {
    const float* x       = (const float*)d_in[0];
    const float* W_hg    = (const float*)d_in[1];
    const float* W_out   = (const float*)d_in[2];
    const float* is_init = (const float*)d_in[3];
    const float* h0      = (const float*)d_in[4];
    float* out = (float*)d_out;
    float* hn  = out + (size_t)M_DIM * H_DIM;

    char* ws = (char*)d_ws;
    size_t off = 0;
    auto alloc = [&](size_t bytes) {
        void* p = ws + off;
        off += (bytes + 255) & ~(size_t)255;
        return p;
    };
    unsigned short* xb  = (unsigned short*)alloc((size_t)M_DIM * K_DIM * 2); // reused as hb
    unsigned short* Wp  = (unsigned short*)alloc((size_t)2 * H_DIM * K_DIM * 2);
    unsigned short* Wob = (unsigned short*)alloc((size_t)H_DIM * K_DIM * 2);
    unsigned short* Sa  = (unsigned short*)alloc((size_t)M_DIM * H_DIM * 2);
    unsigned short* Sb  = (unsigned short*)alloc((size_t)M_DIM * H_DIM * 2);
    float* CA = (float*)alloc((size_t)B_DIM * NCHUNK * H_DIM * 4);
    float* CB = (float*)alloc((size_t)B_DIM * NCHUNK * H_DIM * 4);
    float* CR = (float*)alloc((size_t)B_DIM * NCHUNK * 4);
    float* PA = (float*)alloc((size_t)B_DIM * NCHUNK * H_DIM * 4);
    float* PB = (float*)alloc((size_t)B_DIM * NCHUNK * H_DIM * 4);
    unsigned short* hb = xb;   // alias: x_bf16 dead after GEMM1

    // 1) conversions
    cvt_f32_bf16<<<2048, 256, 0, stream>>>(x, xb, M_DIM * K_DIM / 4);
    prep_whg<<<(2 * H_DIM * K_DIM / 4 + 255) / 256, 256, 0, stream>>>(W_hg, Wp);
    cvt_f32_bf16<<<1024, 256, 0, stream>>>(W_out, Wob, H_DIM * K_DIM / 4);

    // 2) GEMM1 with fused gating epilogue (N = 2048 interleaved cols)
    gemm_bt<1><<<dim3(2048 / 128, M_DIM / 128), 256, 0, stream>>>(
        xb, Wp, nullptr, Sa, Sb, 2048);

    // 3) chunked scan over time
    scan_chunks<<<(B_DIM * NCHUNK * H_DIM) / 256, 256, 0, stream>>>(
        Sa, Sb, is_init, CA, CB, CR);
    scan_tops<<<(B_DIM * H_DIM + 255) / 256, 256, 0, stream>>>(CA, CB, CR, PA, PB);
    scan_apply<<<(B_DIM * NCHUNK * H_DIM) / 256, 256, 0, stream>>>(
        Sa, Sb, is_init, PA, PB, h0, hb, hn);

    // 4) GEMM2: out = h @ W_out^T
    gemm_bt<0><<<dim3(1024 / 128, M_DIM / 128), 256, 0, stream>>>(
        hb, Wob, out, nullptr, nullptr, 1024);
}

// Round 2
// 470.333 us; speedup vs baseline: 2.1914x; 2.1914x over previous
//
#include <hip/hip_runtime.h>
#include <stdint.h>

#define B_DIM 8
#define T_DIM 4096
#define K_DIM 1024
#define H_DIM 1024
#define M_DIM (B_DIM * T_DIM)      // 32768
#define CHUNK 64
#define NCHUNK (T_DIM / CHUNK)     // 64

typedef __attribute__((ext_vector_type(8))) short s16x8;
typedef __attribute__((ext_vector_type(4))) float f32x4;

__device__ __forceinline__ unsigned short f2b(float f) {
    union { float f; uint32_t u; } c; c.f = f;
    uint32_t r = (c.u + 0x7fffu + ((c.u >> 16) & 1u)) >> 16;
    return (unsigned short)r;
}
__device__ __forceinline__ float b2f(unsigned short u) {
    union { uint32_t u; float f; } c; c.u = ((uint32_t)u) << 16;
    return c.f;
}

// async global->LDS, 16B per lane. LDS dest = wave-uniform base + lane*16.
__device__ __forceinline__ void gload_lds16(const unsigned short* g,
                                            unsigned short* l) {
    __builtin_amdgcn_global_load_lds(
        (__attribute__((address_space(1))) void*)g,
        (__attribute__((address_space(3))) void*)l, 16, 0, 0);
}

// ---------------- conversion kernels ----------------

__global__ void cvt_f32_bf16(const float* __restrict__ src,
                             unsigned short* __restrict__ dst, int n4) {
    int stride = gridDim.x * blockDim.x;
    for (int i = blockIdx.x * blockDim.x + threadIdx.x; i < n4; i += stride) {
        float4 v = ((const float4*)src)[i];
        ushort4 o;
        o.x = f2b(v.x); o.y = f2b(v.y); o.z = f2b(v.z); o.w = f2b(v.w);
        ((ushort4*)dst)[i] = o;
    }
}

// W'[2c+0][k] = W_hg[c][k] (hidden row), W'[2c+1][k] = W_hg[H+c][k] (gate row)
__global__ void prep_whg(const float* __restrict__ W,
                         unsigned short* __restrict__ Wp) {
    int i = blockIdx.x * blockDim.x + threadIdx.x;
    int total = 2 * H_DIM * K_DIM / 4;
    if (i >= total) return;
    int e = i * 4;
    int n = e >> 10;          // K = 1024
    int k = e & 1023;
    int src = (n & 1) ? (H_DIM + (n >> 1)) : (n >> 1);
    float4 v = *(const float4*)&W[(size_t)src * K_DIM + k];
    ushort4 o;
    o.x = f2b(v.x); o.y = f2b(v.y); o.z = f2b(v.z); o.w = f2b(v.w);
    *(ushort4*)&Wp[(size_t)n * K_DIM + k] = o;
}

// ---------------- bf16 MFMA GEMM (m97 structure): C[m,n] = sum_k A[m,k]*Bm[n,k]
// 128x128 tile, BK=64, 4 waves, global_load_lds width-16 staging, 2 barriers/K-step.
// EPI==0: plain f32 store. EPI==1: fused minGRU gating epilogue (interleaved cols).

template <int EPI>
__global__ __launch_bounds__(256) void gemm_bt(
    const unsigned short* __restrict__ A,
    const unsigned short* __restrict__ Bm,
    float* __restrict__ C,
    unsigned short* __restrict__ Sa,
    unsigned short* __restrict__ Sb,
    int N) {
    __shared__ unsigned short As[128 * 64];
    __shared__ unsigned short Bs[128 * 64];
    const int K = K_DIM;
    const int m0 = blockIdx.y * 128;
    const int n0 = blockIdx.x * 128;
    const int t = threadIdx.x;
    const int lane = t & 63;
    const int wave = t >> 6;
    const int wm = wave >> 1, wn = wave & 1;

    f32x4 acc[4][4];
#pragma unroll
    for (int m = 0; m < 4; m++)
#pragma unroll
        for (int n = 0; n < 4; n++) acc[m][n] = (f32x4){0.f, 0.f, 0.f, 0.f};

    // staging geometry: segment s = i*4+wave covers LDS bytes [s*1024, s*1024+1024)
    // == rows 8s..8s+7 of the [128][64] bf16 tile; lane l -> row 8s+(l>>3),
    // k-elem (l&7)*8. Global src is per-lane; LDS base is wave-uniform.
    const int grow = lane >> 3;        // 0..7
    const int gcol = (lane & 7) * 8;   // element offset in the 64-wide K slab

    const int l15 = lane & 15;
    const int lk0 = (lane >> 4) * 8;   // fragment k base within slice

    const int KT = K / 64;
    for (int kt = 0; kt < KT; ++kt) {
        const int kof = kt * 64 + gcol;
#pragma unroll
        for (int i = 0; i < 4; i++) {
            const int s = i * 4 + wave;
            gload_lds16(&A[(size_t)(m0 + 8 * s + grow) * K + kof], &As[s * 512]);
            gload_lds16(&Bm[(size_t)(n0 + 8 * s + grow) * K + kof], &Bs[s * 512]);
        }
        __syncthreads();   // drains vmcnt(0): LDS tile complete for all waves
#pragma unroll
        for (int ks = 0; ks < 2; ++ks) {
            const int lk = lk0 + ks * 32;
            s16x8 af[4], bf[4];
#pragma unroll
            for (int m = 0; m < 4; m++)
                af[m] = *(const s16x8*)&As[(wm * 64 + m * 16 + l15) * 64 + lk];
#pragma unroll
            for (int n = 0; n < 4; n++)
                bf[n] = *(const s16x8*)&Bs[(wn * 64 + n * 16 + l15) * 64 + lk];
#pragma unroll
            for (int m = 0; m < 4; m++)
#pragma unroll
                for (int n = 0; n < 4; n++)
                    acc[m][n] = __builtin_amdgcn_mfma_f32_16x16x32_bf16(
                        af[m], bf[n], acc[m][n], 0, 0, 0);
        }
        __syncthreads();   // compute done before next stage overwrites LDS
    }

    const int lr = (lane >> 4) * 4;
#pragma unroll
    for (int m = 0; m < 4; m++) {
#pragma unroll
        for (int n = 0; n < 4; n++) {
#pragma unroll
            for (int r = 0; r < 4; r++) {
                int row = m0 + wm * 64 + m * 16 + lr + r;
                int col = n0 + wn * 64 + n * 16 + l15;
                float v = acc[m][n][r];
                if (EPI == 0) {
                    C[(size_t)row * N + col] = v;
                } else {
                    float o = __shfl_xor(v, 1);
                    int ch = col >> 1;
                    if ((lane & 1) == 0) {
                        // even lane: v = hidden, o = gate logit
                        float g = 1.f / (1.f + __expf(-o));
                        Sb[(size_t)row * H_DIM + ch] = f2b(g * v);
                    } else {
                        // odd lane: v = gate logit
                        float g = 1.f / (1.f + __expf(-v));
                        Sa[(size_t)row * H_DIM + ch] = f2b(1.f - g);
                    }
                }
            }
        }
    }
}

// ---------------- chunked scan ----------------
// Element combine (matches reference): carry (A,Bv); element (a,b,r):
//   r>0 : (A,Bv) = (a, b)      else : (A,Bv) = (a*A, a*Bv + b)

__global__ __launch_bounds__(256) void scan_chunks(
    const unsigned short* __restrict__ Sa, const unsigned short* __restrict__ Sb,
    const float* __restrict__ is_init,
    float* __restrict__ CA, float* __restrict__ CB, float* __restrict__ CR) {
    int idx = blockIdx.x * 256 + threadIdx.x;      // b*65536 + chunk*1024 + ch
    int ch = idx & (H_DIM - 1);
    int chunk = (idx >> 10) & (NCHUNK - 1);
    int b = idx >> 16;
    int t0 = chunk * CHUNK;
    size_t base = ((size_t)b * T_DIM + t0) * H_DIM + ch;
    const float* ii = is_init + (size_t)b * T_DIM + t0;
    float A = 1.f, Bv = 0.f;
    int rf = 0;
    for (int i = 0; i < CHUNK; i++) {
        float a = b2f(Sa[base + (size_t)i * H_DIM]);
        float bb = b2f(Sb[base + (size_t)i * H_DIM]);
        bool rst = ii[i] > 0.f;
        A = rst ? a : a * A;
        Bv = rst ? bb : fmaf(a, Bv, bb);
        rf |= (int)rst;
    }
    size_t o = ((size_t)b * NCHUNK + chunk) * H_DIM + ch;
    CA[o] = A;
    CB[o] = Bv;
    if (ch == 0) CR[b * NCHUNK + chunk] = (float)rf;
}

__global__ void scan_tops(const float* __restrict__ CA, const float* __restrict__ CB,
                          const float* __restrict__ CR,
                          float* __restrict__ PA, float* __restrict__ PB) {
    int idx = blockIdx.x * blockDim.x + threadIdx.x;   // 0 .. B*H-1
    if (idx >= B_DIM * H_DIM) return;
    int ch = idx & (H_DIM - 1);
    int b = idx >> 10;
    float A = 1.f, Bv = 0.f;
    for (int c = 0; c < NCHUNK; c++) {
        size_t o = ((size_t)b * NCHUNK + c) * H_DIM + ch;
        PA[o] = A;            // exclusive prefix
        PB[o] = Bv;
        float a = CA[o], bb = CB[o];
        bool rst = CR[b * NCHUNK + c] > 0.f;
        float nA = rst ? a : a * A;
        float nB = rst ? bb : fmaf(a, Bv, bb);
        A = nA; Bv = nB;
    }
}

__global__ __launch_bounds__(256) void scan_apply(
    const unsigned short* __restrict__ Sa, const unsigned short* __restrict__ Sb,
    const float* __restrict__ is_init,
    const float* __restrict__ PA, const float* __restrict__ PB,
    const float* __restrict__ h0,
    unsigned short* __restrict__ hb, float* __restrict__ hn) {
    int idx = blockIdx.x * 256 + threadIdx.x;
    int ch = idx & (H_DIM - 1);
    int chunk = (idx >> 10) & (NCHUNK - 1);
    int b = idx >> 16;
    int t0 = chunk * CHUNK;
    size_t base = ((size_t)b * T_DIM + t0) * H_DIM + ch;
    const float* ii = is_init + (size_t)b * T_DIM + t0;
    size_t po = ((size_t)b * NCHUNK + chunk) * H_DIM + ch;
    float A = PA[po], Bv = PB[po];
    float h0v = h0[b * H_DIM + ch];
    float h = 0.f;
    for (int i = 0; i < CHUNK; i++) {
        float a = b2f(Sa[base + (size_t)i * H_DIM]);
        float bb = b2f(Sb[base + (size_t)i * H_DIM]);
        bool rst = ii[i] > 0.f;
        A = rst ? a : a * A;
        Bv = rst ? bb : fmaf(a, Bv, bb);
        h = fmaf(A, h0v, Bv);
        hb[base + (size_t)i * H_DIM] = f2b(h);
    }
    if (chunk == NCHUNK - 1) hn[b * H_DIM + ch] = h;
}

// ---------------- launcher ----------------

extern "C" void kernel_launch(void* const* d_in, const int* in_sizes, int n_in,
                              void* d_out, int out_size, void* d_ws, size_t ws_size,
                              hipStream_t stream) {
    const float* x       = (const float*)d_in[0];
    const float* W_hg    = (const float*)d_in[1];
    const float* W_out   = (const float*)d_in[2];
    const float* is_init = (const float*)d_in[3];
    const float* h0      = (const float*)d_in[4];
    float* out = (float*)d_out;
    float* hn  = out + (size_t)M_DIM * H_DIM;

    char* ws = (char*)d_ws;
    size_t off = 0;
    auto alloc = [&](size_t bytes) {
        void* p = ws + off;
        off += (bytes + 255) & ~(size_t)255;
        return p;
    };
    unsigned short* xb  = (unsigned short*)alloc((size_t)M_DIM * K_DIM * 2); // reused as hb
    unsigned short* Wp  = (unsigned short*)alloc((size_t)2 * H_DIM * K_DIM * 2);
    unsigned short* Wob = (unsigned short*)alloc((size_t)H_DIM * K_DIM * 2);
    unsigned short* Sa  = (unsigned short*)alloc((size_t)M_DIM * H_DIM * 2);
    unsigned short* Sb  = (unsigned short*)alloc((size_t)M_DIM * H_DIM * 2);
    float* CA = (float*)alloc((size_t)B_DIM * NCHUNK * H_DIM * 4);
    float* CB = (float*)alloc((size_t)B_DIM * NCHUNK * H_DIM * 4);
    float* CR = (float*)alloc((size_t)B_DIM * NCHUNK * 4);
    float* PA = (float*)alloc((size_t)B_DIM * NCHUNK * H_DIM * 4);
    float* PB = (float*)alloc((size_t)B_DIM * NCHUNK * H_DIM * 4);
    unsigned short* hb = xb;   // alias: x_bf16 dead after GEMM1

    // 1) conversions
    cvt_f32_bf16<<<2048, 256, 0, stream>>>(x, xb, M_DIM * K_DIM / 4);
    prep_whg<<<(2 * H_DIM * K_DIM / 4 + 255) / 256, 256, 0, stream>>>(W_hg, Wp);
    cvt_f32_bf16<<<1024, 256, 0, stream>>>(W_out, Wob, H_DIM * K_DIM / 4);

    // 2) GEMM1 with fused gating epilogue (N = 2048 interleaved cols)
    gemm_bt<1><<<dim3(2048 / 128, M_DIM / 128), 256, 0, stream>>>(
        xb, Wp, nullptr, Sa, Sb, 2048);

    // 3) chunked scan over time
    scan_chunks<<<(B_DIM * NCHUNK * H_DIM) / 256, 256, 0, stream>>>(
        Sa, Sb, is_init, CA, CB, CR);
    scan_tops<<<(B_DIM * H_DIM + 255) / 256, 256, 0, stream>>>(CA, CB, CR, PA, PB);
    scan_apply<<<(B_DIM * NCHUNK * H_DIM) / 256, 256, 0, stream>>>(
        Sa, Sb, is_init, PA, PB, h0, hb, hn);

    // 4) GEMM2: out = h @ W_out^T
    gemm_bt<0><<<dim3(1024 / 128, M_DIM / 128), 256, 0, stream>>>(
        hb, Wob, out, nullptr, nullptr, 1024);
}

// Round 3
// 412.521 us; speedup vs baseline: 2.4985x; 1.1401x over previous
//
#include <hip/hip_runtime.h>
#include <stdint.h>

#define B_DIM 8
#define T_DIM 4096
#define K_DIM 1024
#define H_DIM 1024
#define M_DIM (B_DIM * T_DIM)      // 32768
#define CHUNK 64
#define NCHUNK (T_DIM / CHUNK)     // 64

typedef __attribute__((ext_vector_type(8))) short s16x8;
typedef __attribute__((ext_vector_type(4))) float f32x4;

__device__ __forceinline__ unsigned short f2b(float f) {
    union { float f; uint32_t u; } c; c.f = f;
    uint32_t r = (c.u + 0x7fffu + ((c.u >> 16) & 1u)) >> 16;
    return (unsigned short)r;
}
__device__ __forceinline__ float b2f(unsigned short u) {
    union { uint32_t u; float f; } c; c.u = ((uint32_t)u) << 16;
    return c.f;
}

// async global->LDS, 16B per lane. LDS dest = wave-uniform base + lane*16.
__device__ __forceinline__ void gload_lds16(const unsigned short* g,
                                            unsigned short* l) {
    __builtin_amdgcn_global_load_lds(
        (__attribute__((address_space(1))) void*)g,
        (__attribute__((address_space(3))) void*)l, 16, 0, 0);
}

__device__ __forceinline__ void bar() {
    asm volatile("s_barrier" ::: "memory");
}

// ---------------- conversion kernels ----------------

__global__ void cvt_f32_bf16(const float* __restrict__ src,
                             unsigned short* __restrict__ dst, int n4) {
    int stride = gridDim.x * blockDim.x;
    for (int i = blockIdx.x * blockDim.x + threadIdx.x; i < n4; i += stride) {
        float4 v = ((const float4*)src)[i];
        ushort4 o;
        o.x = f2b(v.x); o.y = f2b(v.y); o.z = f2b(v.z); o.w = f2b(v.w);
        ((ushort4*)dst)[i] = o;
    }
}

// W'[2c+0][k] = W_hg[c][k] (hidden row), W'[2c+1][k] = W_hg[H+c][k] (gate row)
__global__ void prep_whg(const float* __restrict__ W,
                         unsigned short* __restrict__ Wp) {
    int i = blockIdx.x * blockDim.x + threadIdx.x;
    int total = 2 * H_DIM * K_DIM / 4;
    if (i >= total) return;
    int e = i * 4;
    int n = e >> 10;          // K = 1024
    int k = e & 1023;
    int src = (n & 1) ? (H_DIM + (n >> 1)) : (n >> 1);
    float4 v = *(const float4*)&W[(size_t)src * K_DIM + k];
    ushort4 o;
    o.x = f2b(v.x); o.y = f2b(v.y); o.z = f2b(v.z); o.w = f2b(v.w);
    *(ushort4*)&Wp[(size_t)n * K_DIM + k] = o;
}

// ---------------- 256x256 8-phase bf16 MFMA GEMM ----------------
// C[m,n] = sum_k A[m,k] * Bm[n,k].  BM=BN=256, BK=64, 8 waves (2Mx4N),
// dbuf LDS 128KB, XOR slot-swizzle (slot ^= row&7) via pre-swizzled global
// source (rule #21), counted vmcnt(8) at tile boundary, setprio around MFMA.
// EPI==0: f32 store. EPI==1: fused minGRU gating epilogue (interleaved cols).

template <int EPI>
__global__ __launch_bounds__(512, 2) void gemm256(
    const unsigned short* __restrict__ A,
    const unsigned short* __restrict__ Bm,
    float* __restrict__ C,
    unsigned short* __restrict__ Sa,
    unsigned short* __restrict__ Sb,
    int N) {
    __shared__ unsigned short As[2][256 * 64];
    __shared__ unsigned short Bs[2][256 * 64];
    const int K = K_DIM;
    const int KT = K / 64;

    // T1: bijective XCD swizzle (nwg % 8 == 0 for both GEMMs here)
    const int gx = gridDim.x;
    const int nwg = gx * gridDim.y;
    const int orig = blockIdx.y * gx + blockIdx.x;
    const int cpx = nwg >> 3;
    const int wg = (orig & 7) * cpx + (orig >> 3);
    const int m0 = (wg / gx) * 256;
    const int n0 = (wg % gx) * 256;

    const int t = threadIdx.x;
    const int lane = t & 63;
    const int w = t >> 6;               // 0..7
    const int wm = w >> 2, wn = w & 3;  // 2 x 4 wave grid

    // staging lane geometry: within a 1KB segment (8 rows x 128B),
    // lane -> row lrow = lane>>3, linear slot lane&7; pre-swizzled global slot:
    const int lrow = lane >> 3;
    const int lslot = (lane & 7) ^ lrow;

    // fragment-read lane geometry
    const int l15 = lane & 15;
    const int rq = lane >> 4;          // 0..3
    const int rx = l15 & 7;            // row&7 for all fragment rows this lane reads

    f32x4 acc[8][4];
#pragma unroll
    for (int m = 0; m < 8; m++)
#pragma unroll
        for (int n = 0; n < 4; n++) acc[m][n] = (f32x4){0.f, 0.f, 0.f, 0.f};

    // stage one K-tile (A: 4 segs, B: 4 segs per thread; 16KB per 2-instr group)
    auto stage = [&](int kt, int buf) {
#pragma unroll
        for (int j = 0; j < 4; j++) {
            const int seg = j * 8 + w;
            const int row = seg * 8 + lrow;
            gload_lds16(&A[(size_t)(m0 + row) * K + kt * 64 + lslot * 8],
                        &As[buf][seg * 512]);
        }
#pragma unroll
        for (int j = 0; j < 4; j++) {
            const int seg = j * 8 + w;
            const int row = seg * 8 + lrow;
            gload_lds16(&Bm[(size_t)(n0 + row) * K + kt * 64 + lslot * 8],
                        &Bs[buf][seg * 512]);
        }
    };

    s16x8 af[4], bf[4];

    // fragment loads (swizzled read): row r, ks; slot = (rq + ks*4) ^ (r&7)
#define LDA(buf, mi, ks) \
    (*(const s16x8*)&As[buf][(wm * 128 + (mi) * 16 + l15) * 64 + (((rq + (ks) * 4) ^ rx) * 8)])
#define LDB(buf, ni, ks) \
    (*(const s16x8*)&Bs[buf][(wn * 64 + (ni) * 16 + l15) * 64 + (((rq + (ks) * 4) ^ rx) * 8)])

#define MFMA16(MB)                                                          \
    __builtin_amdgcn_s_setprio(1);                                          \
    _Pragma("unroll") for (int m = 0; m < 4; m++)                           \
        _Pragma("unroll") for (int n = 0; n < 4; n++)                       \
            acc[MB + m][n] = __builtin_amdgcn_mfma_f32_16x16x32_bf16(       \
                af[m], bf[n], acc[MB + m][n], 0, 0, 0);                     \
    __builtin_amdgcn_s_setprio(0);

    // prologue: stage tile 0
    stage(0, 0);

    for (int kt = 0; kt < KT; ++kt) {
        const int buf = kt & 1;
        // ---- phase 1: stage next tile, validate current, quadrant (m0-3, ks0)
        if (kt + 1 < KT) {
            stage(kt + 1, buf ^ 1);
            asm volatile("s_waitcnt vmcnt(8)" ::: "memory");  // own tile-kt loads done
        } else {
            asm volatile("s_waitcnt vmcnt(0)" ::: "memory");
        }
        bar();   // all waves validated -> LDS tile kt complete
#pragma unroll
        for (int m = 0; m < 4; m++) af[m] = LDA(buf, m, 0);
#pragma unroll
        for (int n = 0; n < 4; n++) bf[n] = LDB(buf, n, 0);
        bar();
        MFMA16(0);
        bar();
        // ---- phase 2: (m4-7, ks0), reuse bf
#pragma unroll
        for (int m = 0; m < 4; m++) af[m] = LDA(buf, m + 4, 0);
        bar();
        MFMA16(4);
        bar();
        // ---- phase 3: (m0-3, ks1)
#pragma unroll
        for (int m = 0; m < 4; m++) af[m] = LDA(buf, m, 1);
#pragma unroll
        for (int n = 0; n < 4; n++) bf[n] = LDB(buf, n, 1);
        bar();
        MFMA16(0);
        bar();
        // ---- phase 4: (m4-7, ks1)
#pragma unroll
        for (int m = 0; m < 4; m++) af[m] = LDA(buf, m + 4, 1);
        bar();
        MFMA16(4);
        bar();
    }

    // ---- epilogue
    const int lr4 = rq * 4;
#pragma unroll
    for (int m = 0; m < 8; m++) {
#pragma unroll
        for (int n = 0; n < 4; n++) {
#pragma unroll
            for (int r = 0; r < 4; r++) {
                const int row = m0 + wm * 128 + m * 16 + lr4 + r;
                const int col = n0 + wn * 64 + n * 16 + l15;
                float v = acc[m][n][r];
                if (EPI == 0) {
                    C[(size_t)row * N + col] = v;
                } else {
                    float o = __shfl_xor(v, 1);
                    int ch = col >> 1;
                    if ((lane & 1) == 0) {
                        // even lane: v = hidden, o = gate logit
                        float g = 1.f / (1.f + __expf(-o));
                        Sb[(size_t)row * H_DIM + ch] = f2b(g * v);
                    } else {
                        // odd lane: v = gate logit
                        float g = 1.f / (1.f + __expf(-v));
                        Sa[(size_t)row * H_DIM + ch] = f2b(1.f - g);
                    }
                }
            }
        }
    }
#undef LDA
#undef LDB
#undef MFMA16
}

// ---------------- chunked scan ----------------
// Element combine (matches reference): carry (A,Bv); element (a,b,r):
//   r>0 : (A,Bv) = (a, b)      else : (A,Bv) = (a*A, a*Bv + b)

__global__ __launch_bounds__(256) void scan_chunks(
    const unsigned short* __restrict__ Sa, const unsigned short* __restrict__ Sb,
    const float* __restrict__ is_init,
    float* __restrict__ CA, float* __restrict__ CB, float* __restrict__ CR) {
    int idx = blockIdx.x * 256 + threadIdx.x;      // b*65536 + chunk*1024 + ch
    int ch = idx & (H_DIM - 1);
    int chunk = (idx >> 10) & (NCHUNK - 1);
    int b = idx >> 16;
    int t0 = chunk * CHUNK;
    size_t base = ((size_t)b * T_DIM + t0) * H_DIM + ch;
    const float* ii = is_init + (size_t)b * T_DIM + t0;
    float A = 1.f, Bv = 0.f;
    int rf = 0;
    for (int i = 0; i < CHUNK; i++) {
        float a = b2f(Sa[base + (size_t)i * H_DIM]);
        float bb = b2f(Sb[base + (size_t)i * H_DIM]);
        bool rst = ii[i] > 0.f;
        A = rst ? a : a * A;
        Bv = rst ? bb : fmaf(a, Bv, bb);
        rf |= (int)rst;
    }
    size_t o = ((size_t)b * NCHUNK + chunk) * H_DIM + ch;
    CA[o] = A;
    CB[o] = Bv;
    if (ch == 0) CR[b * NCHUNK + chunk] = (float)rf;
}

__global__ void scan_tops(const float* __restrict__ CA, const float* __restrict__ CB,
                          const float* __restrict__ CR,
                          float* __restrict__ PA, float* __restrict__ PB) {
    int idx = blockIdx.x * blockDim.x + threadIdx.x;   // 0 .. B*H-1
    if (idx >= B_DIM * H_DIM) return;
    int ch = idx & (H_DIM - 1);
    int b = idx >> 10;
    float A = 1.f, Bv = 0.f;
    for (int c = 0; c < NCHUNK; c++) {
        size_t o = ((size_t)b * NCHUNK + c) * H_DIM + ch;
        PA[o] = A;            // exclusive prefix
        PB[o] = Bv;
        float a = CA[o], bb = CB[o];
        bool rst = CR[b * NCHUNK + c] > 0.f;
        float nA = rst ? a : a * A;
        float nB = rst ? bb : fmaf(a, Bv, bb);
        A = nA; Bv = nB;
    }
}

__global__ __launch_bounds__(256) void scan_apply(
    const unsigned short* __restrict__ Sa, const unsigned short* __restrict__ Sb,
    const float* __restrict__ is_init,
    const float* __restrict__ PA, const float* __restrict__ PB,
    const float* __restrict__ h0,
    unsigned short* __restrict__ hb, float* __restrict__ hn) {
    int idx = blockIdx.x * 256 + threadIdx.x;
    int ch = idx & (H_DIM - 1);
    int chunk = (idx >> 10) & (NCHUNK - 1);
    int b = idx >> 16;
    int t0 = chunk * CHUNK;
    size_t base = ((size_t)b * T_DIM + t0) * H_DIM + ch;
    const float* ii = is_init + (size_t)b * T_DIM + t0;
    size_t po = ((size_t)b * NCHUNK + chunk) * H_DIM + ch;
    float A = PA[po], Bv = PB[po];
    float h0v = h0[b * H_DIM + ch];
    float h = 0.f;
    for (int i = 0; i < CHUNK; i++) {
        float a = b2f(Sa[base + (size_t)i * H_DIM]);
        float bb = b2f(Sb[base + (size_t)i * H_DIM]);
        bool rst = ii[i] > 0.f;
        A = rst ? a : a * A;
        Bv = rst ? bb : fmaf(a, Bv, bb);
        h = fmaf(A, h0v, Bv);
        hb[base + (size_t)i * H_DIM] = f2b(h);
    }
    if (chunk == NCHUNK - 1) hn[b * H_DIM + ch] = h;
}

// ---------------- launcher ----------------

extern "C" void kernel_launch(void* const* d_in, const int* in_sizes, int n_in,
                              void* d_out, int out_size, void* d_ws, size_t ws_size,
                              hipStream_t stream) {
    const float* x       = (const float*)d_in[0];
    const float* W_hg    = (const float*)d_in[1];
    const float* W_out   = (const float*)d_in[2];
    const float* is_init = (const float*)d_in[3];
    const float* h0      = (const float*)d_in[4];
    float* out = (float*)d_out;
    float* hn  = out + (size_t)M_DIM * H_DIM;

    char* ws = (char*)d_ws;
    size_t off = 0;
    auto alloc = [&](size_t bytes) {
        void* p = ws + off;
        off += (bytes + 255) & ~(size_t)255;
        return p;
    };
    unsigned short* xb  = (unsigned short*)alloc((size_t)M_DIM * K_DIM * 2); // reused as hb
    unsigned short* Wp  = (unsigned short*)alloc((size_t)2 * H_DIM * K_DIM * 2);
    unsigned short* Wob = (unsigned short*)alloc((size_t)H_DIM * K_DIM * 2);
    unsigned short* Sa  = (unsigned short*)alloc((size_t)M_DIM * H_DIM * 2);
    unsigned short* Sb  = (unsigned short*)alloc((size_t)M_DIM * H_DIM * 2);
    float* CA = (float*)alloc((size_t)B_DIM * NCHUNK * H_DIM * 4);
    float* CB = (float*)alloc((size_t)B_DIM * NCHUNK * H_DIM * 4);
    float* CR = (float*)alloc((size_t)B_DIM * NCHUNK * 4);
    float* PA = (float*)alloc((size_t)B_DIM * NCHUNK * H_DIM * 4);
    float* PB = (float*)alloc((size_t)B_DIM * NCHUNK * H_DIM * 4);
    unsigned short* hb = xb;   // alias: x_bf16 dead after GEMM1

    // 1) conversions
    cvt_f32_bf16<<<2048, 256, 0, stream>>>(x, xb, M_DIM * K_DIM / 4);
    prep_whg<<<(2 * H_DIM * K_DIM / 4 + 255) / 256, 256, 0, stream>>>(W_hg, Wp);
    cvt_f32_bf16<<<1024, 256, 0, stream>>>(W_out, Wob, H_DIM * K_DIM / 4);

    // 2) GEMM1 with fused gating epilogue (N = 2048 interleaved cols)
    gemm256<1><<<dim3(2048 / 256, M_DIM / 256), 512, 0, stream>>>(
        xb, Wp, nullptr, Sa, Sb, 2048);

    // 3) chunked scan over time
    scan_chunks<<<(B_DIM * NCHUNK * H_DIM) / 256, 256, 0, stream>>>(
        Sa, Sb, is_init, CA, CB, CR);
    scan_tops<<<(B_DIM * H_DIM + 255) / 256, 256, 0, stream>>>(CA, CB, CR, PA, PB);
    scan_apply<<<(B_DIM * NCHUNK * H_DIM) / 256, 256, 0, stream>>>(
        Sa, Sb, is_init, PA, PB, h0, hb, hn);

    // 4) GEMM2: out = h @ W_out^T
    gemm256<0><<<dim3(1024 / 256, M_DIM / 256), 512, 0, stream>>>(
        hb, Wob, out, nullptr, nullptr, 1024);
}

// Round 4
// 374.559 us; speedup vs baseline: 2.7517x; 1.1014x over previous
//
#include <hip/hip_runtime.h>
#include <stdint.h>

#define B_DIM 8
#define T_DIM 4096
#define K_DIM 1024
#define H_DIM 1024
#define M_DIM (B_DIM * T_DIM)      // 32768
#define CHUNK 64
#define NCHUNK (T_DIM / CHUNK)     // 64

typedef __attribute__((ext_vector_type(8))) short s16x8;
typedef __attribute__((ext_vector_type(4))) float f32x4;

__device__ __forceinline__ unsigned short f2b(float f) {
    union { float f; uint32_t u; } c; c.f = f;
    uint32_t r = (c.u + 0x7fffu + ((c.u >> 16) & 1u)) >> 16;
    return (unsigned short)r;
}
__device__ __forceinline__ float b2f(unsigned short u) {
    union { uint32_t u; float f; } c; c.u = ((uint32_t)u) << 16;
    return c.f;
}

// async global->LDS, 16B per lane. LDS dest = wave-uniform base + lane*16.
__device__ __forceinline__ void gload_lds16(const unsigned short* g,
                                            unsigned short* l) {
    __builtin_amdgcn_global_load_lds(
        (__attribute__((address_space(1))) void*)g,
        (__attribute__((address_space(3))) void*)l, 16, 0, 0);
}

__device__ __forceinline__ void bar() {
    asm volatile("s_barrier" ::: "memory");
}

// ---------------- conversion kernels ----------------

__global__ void cvt_f32_bf16(const float* __restrict__ src,
                             unsigned short* __restrict__ dst, int n4) {
    int stride = gridDim.x * blockDim.x;
    for (int i = blockIdx.x * blockDim.x + threadIdx.x; i < n4; i += stride) {
        float4 v = ((const float4*)src)[i];
        ushort4 o;
        o.x = f2b(v.x); o.y = f2b(v.y); o.z = f2b(v.z); o.w = f2b(v.w);
        ((ushort4*)dst)[i] = o;
    }
}

// W'[2c+0][k] = W_hg[c][k] (hidden row), W'[2c+1][k] = W_hg[H+c][k] (gate row)
__global__ void prep_whg(const float* __restrict__ W,
                         unsigned short* __restrict__ Wp) {
    int i = blockIdx.x * blockDim.x + threadIdx.x;
    int total = 2 * H_DIM * K_DIM / 4;
    if (i >= total) return;
    int e = i * 4;
    int n = e >> 10;          // K = 1024
    int k = e & 1023;
    int src = (n & 1) ? (H_DIM + (n >> 1)) : (n >> 1);
    float4 v = *(const float4*)&W[(size_t)src * K_DIM + k];
    ushort4 o;
    o.x = f2b(v.x); o.y = f2b(v.y); o.z = f2b(v.z); o.w = f2b(v.w);
    *(ushort4*)&Wp[(size_t)n * K_DIM + k] = o;
}

// ---------------- 256x256 8-phase bf16 MFMA GEMM ----------------
// C[m,n] = sum_k A[m,k] * Bm[n,k].  BM=BN=256, BK=64, 8 waves (2Mx4N),
// dbuf LDS 128KB, XOR slot-swizzle via pre-swizzled global source.
// Staging spread 3/3/2 over phases 1-3; pipelined validation vmcnt(0) in
// phase 4 (1-3 phases after issue) -> no phase starts with a memory stall.
// EPI==0: f32 store. EPI==1: fused minGRU gating epilogue (interleaved cols).

template <int EPI>
__global__ __launch_bounds__(512, 2) void gemm256(
    const unsigned short* __restrict__ A,
    const unsigned short* __restrict__ Bm,
    float* __restrict__ C,
    unsigned short* __restrict__ Sa,
    unsigned short* __restrict__ Sb,
    int N) {
    __shared__ unsigned short As[2][256 * 64];
    __shared__ unsigned short Bs[2][256 * 64];
    const int K = K_DIM;
    const int KT = K / 64;

    // T1: bijective XCD swizzle (nwg % 8 == 0 for both GEMMs here)
    const int gx = gridDim.x;
    const int nwg = gx * gridDim.y;
    const int orig = blockIdx.y * gx + blockIdx.x;
    const int cpx = nwg >> 3;
    const int wg = (orig & 7) * cpx + (orig >> 3);
    const int m0 = (wg / gx) * 256;
    const int n0 = (wg % gx) * 256;

    const int t = threadIdx.x;
    const int lane = t & 63;
    const int w = t >> 6;               // 0..7
    const int wm = w >> 2, wn = w & 3;  // 2 x 4 wave grid

    // staging lane geometry: 1KB segment = 8 rows x 128B; lane -> row lane>>3,
    // pre-swizzled global slot (lane&7)^row so linear LDS ends up swizzled.
    const int lrow = lane >> 3;
    const int lslot = (lane & 7) ^ lrow;

    // fragment-read lane geometry
    const int l15 = lane & 15;
    const int rq = lane >> 4;          // 0..3
    const int rx = l15 & 7;            // row&7 for this lane's fragment rows

    f32x4 acc[8][4];
#pragma unroll
    for (int m = 0; m < 8; m++)
#pragma unroll
        for (int n = 0; n < 4; n++) acc[m][n] = (f32x4){0.f, 0.f, 0.f, 0.f};

    // one stage instruction: matrix sel (0=A,1=B), segment group j (0..3)
    auto stageA = [&](int kt, int buf, int j) {
        const int seg = j * 8 + w;
        const int row = seg * 8 + lrow;
        gload_lds16(&A[(size_t)(m0 + row) * K + kt * 64 + lslot * 8],
                    &As[buf][seg * 512]);
    };
    auto stageB = [&](int kt, int buf, int j) {
        const int seg = j * 8 + w;
        const int row = seg * 8 + lrow;
        gload_lds16(&Bm[(size_t)(n0 + row) * K + kt * 64 + lslot * 8],
                    &Bs[buf][seg * 512]);
    };

    s16x8 af[4], bf[4];

#define LDA(buf, mi, ks) \
    (*(const s16x8*)&As[buf][(wm * 128 + (mi) * 16 + l15) * 64 + (((rq + (ks) * 4) ^ rx) * 8)])
#define LDB(buf, ni, ks) \
    (*(const s16x8*)&Bs[buf][(wn * 64 + (ni) * 16 + l15) * 64 + (((rq + (ks) * 4) ^ rx) * 8)])

#define MFMA16(MB)                                                          \
    __builtin_amdgcn_s_setprio(1);                                          \
    _Pragma("unroll") for (int m = 0; m < 4; m++)                           \
        _Pragma("unroll") for (int n = 0; n < 4; n++)                       \
            acc[MB + m][n] = __builtin_amdgcn_mfma_f32_16x16x32_bf16(       \
                af[m], bf[n], acc[MB + m][n], 0, 0, 0);                     \
    __builtin_amdgcn_s_setprio(0);

    // prologue: stage tile 0 fully, validate
    {
#pragma unroll
        for (int j = 0; j < 4; j++) stageA(0, 0, j);
#pragma unroll
        for (int j = 0; j < 4; j++) stageB(0, 0, j);
        asm volatile("s_waitcnt vmcnt(0)" ::: "memory");
        bar();
    }

    for (int kt = 0; kt < KT; ++kt) {
        const int buf = kt & 1;
        const int nb = buf ^ 1;
        const bool nx = (kt + 1 < KT);
        // ---- phase 1: reads (m0-3 + b, ks0); stage 3 loads of kt+1
#pragma unroll
        for (int m = 0; m < 4; m++) af[m] = LDA(buf, m, 0);
#pragma unroll
        for (int n = 0; n < 4; n++) bf[n] = LDB(buf, n, 0);
        if (nx) { stageA(kt + 1, nb, 0); stageA(kt + 1, nb, 1); stageB(kt + 1, nb, 0); }
        bar();
        MFMA16(0);
        bar();
        // ---- phase 2: reads (m4-7, ks0); stage 3
#pragma unroll
        for (int m = 0; m < 4; m++) af[m] = LDA(buf, m + 4, 0);
        if (nx) { stageA(kt + 1, nb, 2); stageA(kt + 1, nb, 3); stageB(kt + 1, nb, 1); }
        bar();
        MFMA16(4);
        bar();
        // ---- phase 3: reads (m0-3 + b, ks1); stage 2
#pragma unroll
        for (int m = 0; m < 4; m++) af[m] = LDA(buf, m, 1);
#pragma unroll
        for (int n = 0; n < 4; n++) bf[n] = LDB(buf, n, 1);
        if (nx) { stageB(kt + 1, nb, 2); stageB(kt + 1, nb, 3); }
        bar();
        MFMA16(0);
        bar();
        // ---- phase 4: reads (m4-7, ks1); pipelined validation of tile kt+1
#pragma unroll
        for (int m = 0; m < 4; m++) af[m] = LDA(buf, m + 4, 1);
        asm volatile("s_waitcnt vmcnt(0)" ::: "memory");  // kt+1 loads done (1-3 phases old)
        bar();   // collective: buf^1 valid for everyone at kt+1 phase 1
        MFMA16(4);
        bar();
    }

    // ---- epilogue
    const int lr4 = rq * 4;
#pragma unroll
    for (int m = 0; m < 8; m++) {
#pragma unroll
        for (int n = 0; n < 4; n++) {
#pragma unroll
            for (int r = 0; r < 4; r++) {
                const int row = m0 + wm * 128 + m * 16 + lr4 + r;
                const int col = n0 + wn * 64 + n * 16 + l15;
                float v = acc[m][n][r];
                if (EPI == 0) {
                    C[(size_t)row * N + col] = v;
                } else {
                    float o = __shfl_xor(v, 1);
                    int ch = col >> 1;
                    if ((lane & 1) == 0) {
                        // even lane: v = hidden, o = gate logit
                        float g = 1.f / (1.f + __expf(-o));
                        Sb[(size_t)row * H_DIM + ch] = f2b(g * v);
                    } else {
                        // odd lane: v = gate logit
                        float g = 1.f / (1.f + __expf(-v));
                        Sa[(size_t)row * H_DIM + ch] = f2b(1.f - g);
                    }
                }
            }
        }
    }
#undef LDA
#undef LDB
#undef MFMA16
}

// ---------------- chunked scan ----------------
// Element combine (matches reference): carry (A,Bv); element (a,b,r):
//   r>0 : (A,Bv) = (a, b)      else : (A,Bv) = (a*A, a*Bv + b)

__global__ __launch_bounds__(256) void scan_chunks(
    const unsigned short* __restrict__ Sa, const unsigned short* __restrict__ Sb,
    const float* __restrict__ is_init,
    float* __restrict__ CA, float* __restrict__ CB, float* __restrict__ CR) {
    int idx = blockIdx.x * 256 + threadIdx.x;      // b*65536 + chunk*1024 + ch
    int ch = idx & (H_DIM - 1);
    int chunk = (idx >> 10) & (NCHUNK - 1);
    int b = idx >> 16;
    int t0 = chunk * CHUNK;
    size_t base = ((size_t)b * T_DIM + t0) * H_DIM + ch;
    const float* ii = is_init + (size_t)b * T_DIM + t0;
    float A = 1.f, Bv = 0.f;
    int rf = 0;
    for (int i = 0; i < CHUNK; i++) {
        float a = b2f(Sa[base + (size_t)i * H_DIM]);
        float bb = b2f(Sb[base + (size_t)i * H_DIM]);
        bool rst = ii[i] > 0.f;
        A = rst ? a : a * A;
        Bv = rst ? bb : fmaf(a, Bv, bb);
        rf |= (int)rst;
    }
    size_t o = ((size_t)b * NCHUNK + chunk) * H_DIM + ch;
    CA[o] = A;
    CB[o] = Bv;
    if (ch == 0) CR[b * NCHUNK + chunk] = (float)rf;
}

__global__ void scan_tops(const float* __restrict__ CA, const float* __restrict__ CB,
                          const float* __restrict__ CR,
                          float* __restrict__ PA, float* __restrict__ PB) {
    int idx = blockIdx.x * blockDim.x + threadIdx.x;   // 0 .. B*H-1
    if (idx >= B_DIM * H_DIM) return;
    int ch = idx & (H_DIM - 1);
    int b = idx >> 10;
    float A = 1.f, Bv = 0.f;
    for (int c = 0; c < NCHUNK; c++) {
        size_t o = ((size_t)b * NCHUNK + c) * H_DIM + ch;
        PA[o] = A;            // exclusive prefix
        PB[o] = Bv;
        float a = CA[o], bb = CB[o];
        bool rst = CR[b * NCHUNK + c] > 0.f;
        float nA = rst ? a : a * A;
        float nB = rst ? bb : fmaf(a, Bv, bb);
        A = nA; Bv = nB;
    }
}

__global__ __launch_bounds__(256) void scan_apply(
    const unsigned short* __restrict__ Sa, const unsigned short* __restrict__ Sb,
    const float* __restrict__ is_init,
    const float* __restrict__ PA, const float* __restrict__ PB,
    const float* __restrict__ h0,
    unsigned short* __restrict__ hb, float* __restrict__ hn) {
    int idx = blockIdx.x * 256 + threadIdx.x;
    int ch = idx & (H_DIM - 1);
    int chunk = (idx >> 10) & (NCHUNK - 1);
    int b = idx >> 16;
    int t0 = chunk * CHUNK;
    size_t base = ((size_t)b * T_DIM + t0) * H_DIM + ch;
    const float* ii = is_init + (size_t)b * T_DIM + t0;
    size_t po = ((size_t)b * NCHUNK + chunk) * H_DIM + ch;
    float A = PA[po], Bv = PB[po];
    float h0v = h0[b * H_DIM + ch];
    float h = 0.f;
    for (int i = 0; i < CHUNK; i++) {
        float a = b2f(Sa[base + (size_t)i * H_DIM]);
        float bb = b2f(Sb[base + (size_t)i * H_DIM]);
        bool rst = ii[i] > 0.f;
        A = rst ? a : a * A;
        Bv = rst ? bb : fmaf(a, Bv, bb);
        h = fmaf(A, h0v, Bv);
        hb[base + (size_t)i * H_DIM] = f2b(h);
    }
    if (chunk == NCHUNK - 1) hn[b * H_DIM + ch] = h;
}

// ---------------- launcher ----------------

extern "C" void kernel_launch(void* const* d_in, const int* in_sizes, int n_in,
                              void* d_out, int out_size, void* d_ws, size_t ws_size,
                              hipStream_t stream) {
    const float* x       = (const float*)d_in[0];
    const float* W_hg    = (const float*)d_in[1];
    const float* W_out   = (const float*)d_in[2];
    const float* is_init = (const float*)d_in[3];
    const float* h0      = (const float*)d_in[4];
    float* out = (float*)d_out;
    float* hn  = out + (size_t)M_DIM * H_DIM;

    char* ws = (char*)d_ws;
    size_t off = 0;
    auto alloc = [&](size_t bytes) {
        void* p = ws + off;
        off += (bytes + 255) & ~(size_t)255;
        return p;
    };
    unsigned short* xb  = (unsigned short*)alloc((size_t)M_DIM * K_DIM * 2); // reused as hb
    unsigned short* Wp  = (unsigned short*)alloc((size_t)2 * H_DIM * K_DIM * 2);
    unsigned short* Wob = (unsigned short*)alloc((size_t)H_DIM * K_DIM * 2);
    unsigned short* Sa  = (unsigned short*)alloc((size_t)M_DIM * H_DIM * 2);
    unsigned short* Sb  = (unsigned short*)alloc((size_t)M_DIM * H_DIM * 2);
    float* CA = (float*)alloc((size_t)B_DIM * NCHUNK * H_DIM * 4);
    float* CB = (float*)alloc((size_t)B_DIM * NCHUNK * H_DIM * 4);
    float* CR = (float*)alloc((size_t)B_DIM * NCHUNK * 4);
    float* PA = (float*)alloc((size_t)B_DIM * NCHUNK * H_DIM * 4);
    float* PB = (float*)alloc((size_t)B_DIM * NCHUNK * H_DIM * 4);
    unsigned short* hb = xb;   // alias: x_bf16 dead after GEMM1

    // 1) conversions
    cvt_f32_bf16<<<2048, 256, 0, stream>>>(x, xb, M_DIM * K_DIM / 4);
    prep_whg<<<(2 * H_DIM * K_DIM / 4 + 255) / 256, 256, 0, stream>>>(W_hg, Wp);
    cvt_f32_bf16<<<1024, 256, 0, stream>>>(W_out, Wob, H_DIM * K_DIM / 4);

    // 2) GEMM1 with fused gating epilogue (N = 2048 interleaved cols)
    gemm256<1><<<dim3(2048 / 256, M_DIM / 256), 512, 0, stream>>>(
        xb, Wp, nullptr, Sa, Sb, 2048);

    // 3) chunked scan over time
    scan_chunks<<<(B_DIM * NCHUNK * H_DIM) / 256, 256, 0, stream>>>(
        Sa, Sb, is_init, CA, CB, CR);
    scan_tops<<<(B_DIM * H_DIM + 255) / 256, 256, 0, stream>>>(CA, CB, CR, PA, PB);
    scan_apply<<<(B_DIM * NCHUNK * H_DIM) / 256, 256, 0, stream>>>(
        Sa, Sb, is_init, PA, PB, h0, hb, hn);

    // 4) GEMM2: out = h @ W_out^T
    gemm256<0><<<dim3(1024 / 256, M_DIM / 256), 512, 0, stream>>>(
        hb, Wob, out, nullptr, nullptr, 1024);
}